// Round 1
// baseline (160.877 us; speedup 1.0000x reference)
//
#include <hip/hip_runtime.h>
#include <math.h>

#define THREADS 256
#define QPT 4                    // query points per thread
#define QPB (THREADS * QPT)      // 1024 query points per block
#define CHUNK 256                // db points staged in LDS per block

// Fill min arrays with +inf (bit pattern 0x7f800000). Workspace is re-poisoned
// to 0xAA before every timed launch, so this must run every call.
__global__ void init_ws_kernel(unsigned* __restrict__ mins, int total) {
    int i = blockIdx.x * blockDim.x + threadIdx.x;
    if (i < total) mins[i] = 0x7f800000u;
}

// For each query point, min squared distance to a CHUNK of db points.
// Partial mins merged across chunk-blocks with atomicMin on uint bits
// (valid: squared distances are non-negative, so float order == uint order).
__global__ __launch_bounds__(THREADS) void chamfer_min_kernel(
        const float* __restrict__ q, int nq,
        const float* __restrict__ db, int ndb,
        unsigned* __restrict__ outMin) {
    __shared__ float s[CHUNK * 3];
    const int tid = threadIdx.x;
    const int cstart = blockIdx.y * CHUNK;

    // Stage db chunk into LDS (768 floats, coalesced).
    for (int e = tid; e < CHUNK * 3; e += THREADS) {
        int g = cstart * 3 + e;
        s[e] = (g < ndb * 3) ? db[g] : 1.0e30f;  // OOB pad -> huge distance
    }

    // Load this thread's 4 query points into registers.
    float qx[QPT], qy[QPT], qz[QPT], mn[QPT];
    int qidx[QPT];
    const int qbase = blockIdx.x * QPB + tid;
#pragma unroll
    for (int p = 0; p < QPT; ++p) {
        int idx = qbase + p * THREADS;
        qidx[p] = idx;
        if (idx < nq) {
            qx[p] = q[idx * 3 + 0];
            qy[p] = q[idx * 3 + 1];
            qz[p] = q[idx * 3 + 2];
        } else {
            qx[p] = qy[p] = qz[p] = 3.0e30f;  // never written back
        }
        mn[p] = 3.0e38f;
    }
    __syncthreads();

    // Inner loop: 3 LDS broadcast reads amortized over QPT=4 query points
    // (28 VALU inst per 3 ds_read_b32 -> VALU-bound).
#pragma unroll 8
    for (int t = 0; t < CHUNK; ++t) {
        float tx = s[3 * t + 0];
        float ty = s[3 * t + 1];
        float tz = s[3 * t + 2];
#pragma unroll
        for (int p = 0; p < QPT; ++p) {
            float dx = qx[p] - tx;
            float dy = qy[p] - ty;
            float dz = qz[p] - tz;
            float d = fmaf(dz, dz, fmaf(dy, dy, dx * dx));
            mn[p] = fminf(mn[p], d);
        }
    }

#pragma unroll
    for (int p = 0; p < QPT; ++p) {
        if (qidx[p] < nq) {
            atomicMin(&outMin[qidx[p]], __float_as_uint(mn[p]));
        }
    }
}

// Single-block reduction: mean(sqrt(minF)) and mean(sqrt(minB)), average.
__global__ __launch_bounds__(256) void finalize_kernel(
        const unsigned* __restrict__ minF, int n,
        const unsigned* __restrict__ minB, int m,
        float* __restrict__ out) {
    float sf = 0.0f, sb = 0.0f;
    for (int i = threadIdx.x; i < n; i += 256) sf += sqrtf(__uint_as_float(minF[i]));
    for (int i = threadIdx.x; i < m; i += 256) sb += sqrtf(__uint_as_float(minB[i]));

    // wave=64 butterfly
    for (int off = 32; off > 0; off >>= 1) {
        sf += __shfl_down(sf, off, 64);
        sb += __shfl_down(sb, off, 64);
    }
    __shared__ float wf[4], wb[4];
    int lane = threadIdx.x & 63;
    int wave = threadIdx.x >> 6;
    if (lane == 0) { wf[wave] = sf; wb[wave] = sb; }
    __syncthreads();
    if (threadIdx.x == 0) {
        float tf = wf[0] + wf[1] + wf[2] + wf[3];
        float tb = wb[0] + wb[1] + wb[2] + wb[3];
        out[0] = 0.5f * (tf / (float)n + tb / (float)m);
    }
}

extern "C" void kernel_launch(void* const* d_in, const int* in_sizes, int n_in,
                              void* d_out, int out_size, void* d_ws, size_t ws_size,
                              hipStream_t stream) {
    const float* pred   = (const float*)d_in[0];
    const float* target = (const float*)d_in[1];
    const int n = in_sizes[0] / 3;   // 16384
    const int m = in_sizes[1] / 3;   // 16384

    unsigned* minF = (unsigned*)d_ws;       // n floats (as uint bits)
    unsigned* minB = minF + n;              // m floats
    float* out = (float*)d_out;

    const int total = n + m;
    init_ws_kernel<<<(total + 255) / 256, 256, 0, stream>>>(minF, total);

    // forward: pred queries vs target db
    dim3 gridF((n + QPB - 1) / QPB, (m + CHUNK - 1) / CHUNK);
    chamfer_min_kernel<<<gridF, THREADS, 0, stream>>>(pred, n, target, m, minF);

    // backward: target queries vs pred db
    dim3 gridB((m + QPB - 1) / QPB, (n + CHUNK - 1) / CHUNK);
    chamfer_min_kernel<<<gridB, THREADS, 0, stream>>>(target, m, pred, n, minB);

    finalize_kernel<<<1, 256, 0, stream>>>(minF, n, minB, m, out);
}

// Round 2
// 122.540 us; speedup vs baseline: 1.3129x; 1.3129x over previous
//
#include <hip/hip_runtime.h>
#include <math.h>

#define THREADS 256
#define QPT 8                     // query points per thread
#define QPB (THREADS * QPT)       // 2048 query points per block
#define CHUNK 256                 // db points staged in LDS per block
#define INF_BITS 0x7f800000u

// ws layout: [minF: n uints][minB: m uints][accF, accB: 2 floats][counter: 1 uint]
// Everything re-poisoned to 0xAA each call -> init kernel runs every call.
__global__ void init_ws_kernel(unsigned* __restrict__ ws, int total /* n+m */) {
    int i = blockIdx.x * blockDim.x + threadIdx.x;
    if (i < total) ws[i] = INF_BITS;
    else if (i < total + 4) ws[i] = 0u;   // accF, accB, counter (+1 spare)
}

// Fused both-direction min-squared-distance kernel.
// grid = (nq/QPB, ndb/CHUNK, 2); z=0: pred->target, z=1: target->pred.
// Partial mins merged via atomicMin on uint bits (sq dists >= 0, so
// float order == uint order).
__global__ __launch_bounds__(THREADS) void chamfer_main_kernel(
        const float* __restrict__ pred, int n,
        const float* __restrict__ target, int m,
        unsigned* __restrict__ minF, unsigned* __restrict__ minB) {
    const int dir = blockIdx.z;
    const float* __restrict__ q  = dir ? target : pred;
    const float* __restrict__ db = dir ? pred : target;
    const int nq  = dir ? m : n;
    const int ndb = dir ? n : m;
    unsigned* __restrict__ outMin = dir ? minB : minF;

    __shared__ alignas(16) float4 s4[CHUNK * 3 / 4];   // 192 float4 = 3 KB
    const int tid = threadIdx.x;
    const int cstart = blockIdx.y * CHUNK;

    // Stage db chunk into LDS as float4 (cstart*3 floats = 16B-aligned since
    // CHUNK=256). Fast path when the whole chunk is in range.
    if (cstart + CHUNK <= ndb) {
        const float4* __restrict__ g4 = (const float4*)(db + (size_t)cstart * 3);
        if (tid < CHUNK * 3 / 4) s4[tid] = g4[tid];
    } else {
        float* s = (float*)s4;
        for (int e = tid; e < CHUNK * 3; e += THREADS) {
            int g = cstart * 3 + e;
            s[e] = (g < ndb * 3) ? db[g] : 1.0e30f;
        }
    }

    // This thread's 8 query points in registers.
    float qx[QPT], qy[QPT], qz[QPT], mn[QPT];
    const int qbase = blockIdx.x * QPB + tid;
#pragma unroll
    for (int p = 0; p < QPT; ++p) {
        int idx = qbase + p * THREADS;
        if (idx < nq) {
            qx[p] = q[idx * 3 + 0];
            qy[p] = q[idx * 3 + 1];
            qz[p] = q[idx * 3 + 2];
        } else {
            qx[p] = qy[p] = qz[p] = 3.0e30f;
        }
        mn[p] = 3.0e38f;
    }
    __syncthreads();

    // Inner loop over db points, 4 at a time via 3 ds_read_b128.
    // Per group: 3 LDS b128 (broadcast) + 8q*4t*7 = 224 VALU inst.
#pragma unroll 2
    for (int g = 0; g < CHUNK / 4; ++g) {
        float4 f0 = s4[3 * g + 0];
        float4 f1 = s4[3 * g + 1];
        float4 f2 = s4[3 * g + 2];
        float tx[4] = {f0.x, f0.w, f1.z, f2.y};
        float ty[4] = {f0.y, f1.x, f1.w, f2.z};
        float tz[4] = {f0.z, f1.y, f2.x, f2.w};
#pragma unroll
        for (int t = 0; t < 4; ++t) {
#pragma unroll
            for (int p = 0; p < QPT; ++p) {
                float dx = qx[p] - tx[t];
                float dy = qy[p] - ty[t];
                float dz = qz[p] - tz[t];
                float d = fmaf(dz, dz, fmaf(dy, dy, dx * dx));
                mn[p] = fminf(mn[p], d);
            }
        }
    }

#pragma unroll
    for (int p = 0; p < QPT; ++p) {
        int idx = qbase + p * THREADS;
        if (idx < nq) atomicMin(&outMin[idx], __float_as_uint(mn[p]));
    }
}

// Parallel reduce: blocks [0, nbF) cover minF, rest cover minB.
// Block sums atomicAdd'd into accF/accB; last block (device atomic counter)
// writes the final scalar, reading accs via atomicAdd(+0) for coherence.
__global__ __launch_bounds__(256) void reduce_final_kernel(
        const unsigned* __restrict__ minF, int n,
        const unsigned* __restrict__ minB, int m,
        float* __restrict__ acc, unsigned* __restrict__ counter,
        float* __restrict__ out, int nbF, int nblocks) {
    const int b = blockIdx.x;
    const bool isF = b < nbF;
    const unsigned* src = isF ? minF : minB;
    const int base = (isF ? b : b - nbF) * 256;
    const int lim = isF ? n : m;
    const int i = base + threadIdx.x;

    float v = (i < lim) ? sqrtf(__uint_as_float(src[i])) : 0.0f;

    // wave64 butterfly + cross-wave LDS combine
    for (int off = 32; off > 0; off >>= 1) v += __shfl_down(v, off, 64);
    __shared__ float w[4];
    int lane = threadIdx.x & 63;
    int wave = threadIdx.x >> 6;
    if (lane == 0) w[wave] = v;
    __syncthreads();

    if (threadIdx.x == 0) {
        float bs = w[0] + w[1] + w[2] + w[3];
        atomicAdd(&acc[isF ? 0 : 1], bs);
        __threadfence();
        unsigned done = atomicAdd(counter, 1u);
        if (done == (unsigned)(nblocks - 1)) {
            float tf = atomicAdd(&acc[0], 0.0f);   // atomic read at coherent point
            float tb = atomicAdd(&acc[1], 0.0f);
            out[0] = 0.5f * (tf / (float)n + tb / (float)m);
        }
    }
}

extern "C" void kernel_launch(void* const* d_in, const int* in_sizes, int n_in,
                              void* d_out, int out_size, void* d_ws, size_t ws_size,
                              hipStream_t stream) {
    const float* pred   = (const float*)d_in[0];
    const float* target = (const float*)d_in[1];
    const int n = in_sizes[0] / 3;   // 16384
    const int m = in_sizes[1] / 3;   // 16384

    unsigned* minF = (unsigned*)d_ws;
    unsigned* minB = minF + n;
    float* acc = (float*)(minB + m);          // acc[0]=F sum, acc[1]=B sum
    unsigned* counter = (unsigned*)(acc + 2);
    float* out = (float*)d_out;

    const int total = n + m;
    init_ws_kernel<<<(total + 4 + 255) / 256, 256, 0, stream>>>((unsigned*)d_ws, total);

    // Fused main: assumes n==m for grid shape; guards handle remainder.
    int gx = (n + QPB - 1) / QPB;             // 8
    int gy = (m + CHUNK - 1) / CHUNK;         // 64
    dim3 grid(gx, gy, 2);
    chamfer_main_kernel<<<grid, THREADS, 0, stream>>>(pred, n, target, m, minF, minB);

    int nbF = (n + 255) / 256;
    int nbB = (m + 255) / 256;
    reduce_final_kernel<<<nbF + nbB, 256, 0, stream>>>(minF, n, minB, m,
                                                       acc, counter, out,
                                                       nbF, nbF + nbB);
}